// Round 12
// baseline (215.001 us; speedup 1.0000x reference)
//
#include <hip/hip_runtime.h>

// TAM fused kernel round 12: register-resident columns, one sample per WAVE,
// ZERO block barriers (wave-local lgkm syncs only; the 2 waves in a 128-block
// never interact). Lane l owns x column col=l (10 f4) and, for l<20, col=64+l
// -> x stays in 80 VGPR; no 13.4KB LDS round trip, no phase-1 vmcnt(0)+barrier
// drain. Stores per t: 1024B + 320B dense sector-aligned NT bursts.
// LDS 3.84KB/wave (pool partials + coef scratch, overlaid).
// NT stores (R6), plain x loads (L3 retention), direct weight reads (R11).
// C=12, T=10, H*W=28, K=3.

#define CC 12
#define TT 10
#define SAMPLE 3360
#define EPSF 1e-5f

typedef float f4 __attribute__((ext_vector_type(4)));

#define FENCE() __builtin_amdgcn_sched_barrier(0)
// Wave-local LDS producer->consumer fence (lanes are lockstep within a wave).
#define WSYNC() do { asm volatile("s_waitcnt lgkmcnt(0)" ::: "memory"); FENCE(); } while (0)

// Per-wave LDS scratch p[960] (floats):
//   ph[840]   @0    : hsum partials ph[t*84+col]      (phase 1 -> 2)
//   overlay on ph after pooling:
//   sz[240]   @0    : G hidden                        (phase 3 -> 4)
//   sa1[30]   @240  : L hidden                        (phase 3 -> 4)
//   skern[36] @280  : k0[12] k1[12] k2[12]            (phase 4 -> 5)
//   sact[120] @320  : sigmoid gate [c][t]             (phase 4 -> 5)
//   pooled[120]@840 : pooled[c][t]                    (phase 2 -> 3)

__global__ __launch_bounds__(128) void tam_kernel(
    const float* __restrict__ x,
    const float* __restrict__ w_g1,
    const float* __restrict__ g1_gamma, const float* __restrict__ g1_beta,
    const float* __restrict__ g1_mean,  const float* __restrict__ g1_var,
    const float* __restrict__ w_g2,
    const float* __restrict__ w_l1,
    const float* __restrict__ l1_gamma, const float* __restrict__ l1_beta,
    const float* __restrict__ l1_mean,  const float* __restrict__ l1_var,
    const float* __restrict__ w_l2,
    float* __restrict__ out)
{
    __shared__ float scr[2][960];

    const int tid  = threadIdx.x;
    const int w    = tid >> 6;
    const int lane = tid & 63;
    float* p = scr[w];

    const int n = blockIdx.x * 2 + w;
    const f4* xg = reinterpret_cast<const f4*>(x + (size_t)n * SAMPLE);
    f4*       og = reinterpret_cast<f4*>(out + (size_t)n * SAMPLE);

    // column ownership: colA = lane (0..63); colB = 64+lane (lanes 0..19)
    const int colA  = lane;
    const int cA    = colA / 7;
    const int baseA = 63 * cA + colA;          // f4 idx = 63c + col + 7t
    const int colB  = 64 + lane;
    const int cB    = colB / 7;
    const int baseB = 63 * cB + colB;
    const bool hasB = (lane < 20);

    // ---- phase 1: load columns into registers (single burst, 20 instrs) ----
    f4 xa[TT], xb[TT];
    #pragma unroll
    for (int t = 0; t < TT; ++t) xa[t] = xg[baseA + 7 * t];
    if (hasB) {
        #pragma unroll
        for (int t = 0; t < TT; ++t) xb[t] = xg[baseB + 7 * t];
    }
    // hsum partials -> ph[t*84+col]
    #pragma unroll
    for (int t = 0; t < TT; ++t)
        p[t * 84 + colA] = xa[t].x + xa[t].y + xa[t].z + xa[t].w;
    if (hasB) {
        #pragma unroll
        for (int t = 0; t < TT; ++t)
            p[t * 84 + colB] = xb[t].x + xb[t].y + xb[t].z + xb[t].w;
    }
    WSYNC();

    // ---- phase 2: pooled[c][t] = (1/28) * sum_{s4<7} ph[t*84+c*7+s4] ----
    #pragma unroll
    for (int q = 0; q < 2; ++q) {
        const int r = lane + q * 64;
        if (r < 120) {
            const int c = r / TT, t = r % TT;
            const float* b = &p[t * 84 + c * 7];
            float s = b[0];
            #pragma unroll
            for (int i = 1; i < 7; ++i) s += b[i];
            p[840 + r] = s * (1.0f / 28.0f);
        }
    }
    WSYNC();

    // ---- phase 3: G hidden (tasks 0..239) + L conv1 (240..269) ----
    #pragma unroll
    for (int q = 0; q < 5; ++q) {
        const int task = lane + q * 64;
        if (task < 240) {
            const int c = task / 20, j = task % 20;
            float s = 0.f;
            #pragma unroll
            for (int t = 0; t < TT; ++t)
                s += p[840 + c * TT + t] * w_g1[j * TT + t];
            const float rs = rsqrtf(g1_var[j] + EPSF);
            p[task] = fmaxf((s - g1_mean[j]) * rs * g1_gamma[j] + g1_beta[j], 0.f);
        } else if (task < 270) {
            const int e = task - 240;
            const int m = e / TT, t = e % TT;
            float s = 0.f;
            #pragma unroll
            for (int c = 0; c < CC; ++c) {
                #pragma unroll
                for (int k = 0; k < 3; ++k) {
                    const int t2 = t + k - 1;
                    if (t2 >= 0 && t2 < TT)
                        s += p[840 + c * TT + t2] * w_l1[(m * CC + c) * 3 + k];
                }
            }
            const float rs = rsqrtf(l1_var[m] + EPSF);
            p[240 + e] = fmaxf((s - l1_mean[m]) * rs * l1_gamma[m] + l1_beta[m], 0.f);
        }
    }
    WSYNC();

    // ---- phase 4: softmax kern (tasks 0..11) + conv2+sigmoid (12..131) ----
    #pragma unroll
    for (int q = 0; q < 3; ++q) {
        const int task = lane + q * 64;
        if (task < CC) {
            const int c = task;
            float sc0 = 0.f, sc1 = 0.f, sc2 = 0.f;
            #pragma unroll
            for (int j = 0; j < 20; ++j) {
                const float zj = p[c * 20 + j];
                sc0 += zj * w_g2[j];
                sc1 += zj * w_g2[20 + j];
                sc2 += zj * w_g2[40 + j];
            }
            const float mx = fmaxf(sc0, fmaxf(sc1, sc2));
            const float e0 = __expf(sc0 - mx), e1 = __expf(sc1 - mx), e2 = __expf(sc2 - mx);
            const float ri = 1.0f / (e0 + e1 + e2);
            p[280 + c] = e0 * ri;
            p[292 + c] = e1 * ri;
            p[304 + c] = e2 * ri;
        } else if (task < 132) {
            const int e = task - 12;
            const int c = e / TT, t = e % TT;
            float s = 0.f;
            #pragma unroll
            for (int m = 0; m < 3; ++m) s += p[240 + m * TT + t] * w_l2[c * 3 + m];
            p[320 + e] = 1.0f / (1.0f + __expf(-s));
        }
    }
    WSYNC();

    // ---- phase 5: apply from registers, dense sector-aligned NT stores ----
    {
        const float k0 = p[280 + cA];
        const float k1 = p[292 + cA];
        const float k2 = p[304 + cA];
        const float* ac = &p[320 + cA * TT];
        #pragma unroll
        for (int t = 0; t < TT; ++t) {
            f4 acc = (k1 * ac[t]) * xa[t];
            if (t > 0)      acc += (k0 * ac[t - 1]) * xa[t - 1];
            if (t < TT - 1) acc += (k2 * ac[t + 1]) * xa[t + 1];
            __builtin_nontemporal_store(acc, og + t * 84 + colA);
        }
    }
    if (hasB) {
        const float k0 = p[280 + cB];
        const float k1 = p[292 + cB];
        const float k2 = p[304 + cB];
        const float* ac = &p[320 + cB * TT];
        #pragma unroll
        for (int t = 0; t < TT; ++t) {
            f4 acc = (k1 * ac[t]) * xb[t];
            if (t > 0)      acc += (k0 * ac[t - 1]) * xb[t - 1];
            if (t < TT - 1) acc += (k2 * ac[t + 1]) * xb[t + 1];
            __builtin_nontemporal_store(acc, og + t * 84 + colB);
        }
    }
}

extern "C" void kernel_launch(void* const* d_in, const int* in_sizes, int n_in,
                              void* d_out, int out_size, void* d_ws, size_t ws_size,
                              hipStream_t stream) {
    (void)n_in; (void)out_size; (void)d_ws; (void)ws_size;
    const float* x        = (const float*)d_in[0];
    const float* w_g1     = (const float*)d_in[1];
    const float* g1_gamma = (const float*)d_in[2];
    const float* g1_beta  = (const float*)d_in[3];
    const float* g1_mean  = (const float*)d_in[4];
    const float* g1_var   = (const float*)d_in[5];
    const float* w_g2     = (const float*)d_in[6];
    const float* w_l1     = (const float*)d_in[7];
    const float* l1_gamma = (const float*)d_in[8];
    const float* l1_beta  = (const float*)d_in[9];
    const float* l1_mean  = (const float*)d_in[10];
    const float* l1_var   = (const float*)d_in[11];
    const float* w_l2     = (const float*)d_in[12];
    float* out = (float*)d_out;

    const int n_total = in_sizes[0] / SAMPLE;     // 32768
    const int blocks  = (n_total + 1) / 2;        // 2 wave-samples per block
    tam_kernel<<<blocks, 128, 0, stream>>>(
        x, w_g1, g1_gamma, g1_beta, g1_mean, g1_var, w_g2,
        w_l1, l1_gamma, l1_beta, l1_mean, l1_var, w_l2, out);
}